// Round 9
// baseline (180.375 us; speedup 1.0000x reference)
//
#include <hip/hip_runtime.h>
#include <hip/hip_bf16.h>

#define N_NODES 50000
#define N_EDGES 800000
#define N_GRAPHS 1024
#define D_IN 64
#define D_PROT 1280
#define HID 256
#define N_PAD 50048   // N_NODES padded to multiple of 64

#define NB 782        // ceil(50048/64) aggregation tiles
#define NCAP 64       // per-node edge-run capacity (deg ~Poisson(16); P(>=64)~1e-19)
#define BEPB 2048     // edges per scatter chunk
#define NCHK 391      // ceil(800000/2048); last chunk rem=1280 (mult of 4)
#define SCAT (NCHK * 8)  // 3128 scatter blocks: (chunk, xcd-partition) pairs

typedef __attribute__((ext_vector_type(8))) short short8;
typedef __attribute__((ext_vector_type(4))) float f32x4;
typedef __hip_bfloat16 bf16;

// round-to-nearest-even f32 -> bf16 bits (finite inputs only)
__device__ inline unsigned bf16rne(float f) {
  unsigned u = __float_as_uint(f);
  return (u + 0x7fffu + ((u >> 16) & 1u)) >> 16;
}
// accumulate 4 bf16 packed in uint2 into float4
__device__ inline void acc_bf2(float4& a, uint2 v) {
  a.x += __uint_as_float(v.x << 16);
  a.y += __uint_as_float(v.x & 0xffff0000u);
  a.z += __uint_as_float(v.y << 16);
  a.w += __uint_as_float(v.y & 0xffff0000u);
}

// ---------------------------------------------------------------------------
// K1 "front": blockIdx [0,SCAT) = XCD-PARTITIONED direct edge-run scatter.
// Block (chunk, p=b&7) reads chunk's 2048 edges (int4, L3-served on re-reads)
// and scatters ONLY dsts with ((d>>6)&7)==p. With round-robin blockIdx->XCD,
// partition p's write lines + ncnt lines are touched by one XCD only ->
// lines accumulate in the local L2, write back once (R6 measured the
// unpartitioned version at 55MB write-RMW / 18% BW / 48us).
// Rest of blocks = conversions + weight packing (BW-bound), unchanged.
// ---------------------------------------------------------------------------
#define PREP_XC 3125                  // 50000*64/4 float4s / 256
#define PREP_PE (PREP_XC + 1280)      // 1024*1280/4 / 256
#define PREP_PL (PREP_PE + 8)         // Wl: 16 coltiles * 2 kc * 64 / 256
#define PREP_PR (PREP_PL + 8)         // Wr
#define PREP_WP (PREP_PR + 160)       // Wp: 16 * 40 * 64 / 256
#define PREP_WI (PREP_WP + 64)        // Wi: 16 * 16 * 64 / 256

__device__ inline void pack_frag(const float* __restrict__ src, bf16* __restrict__ dst,
                                 int KC, int tid) {
  int lane = tid & 63;
  int chunk = tid >> 6;            // = c*KC + kc
  int c = chunk / KC, kc = chunk - c * KC;
  int kbase = kc * 32 + ((lane >> 4) * 8);
  int n = c * 16 + (lane & 15);
#pragma unroll
  for (int j = 0; j < 8; ++j)
    dst[(size_t)tid * 8 + j] = __float2bfloat16(src[(size_t)(kbase + j) * HID + n]);
}

__global__ __launch_bounds__(256) void k_front(
    const float* __restrict__ x, const float* __restrict__ pe,
    const float* __restrict__ Wl, const float* __restrict__ Wr,
    const float* __restrict__ Wp, const float* __restrict__ Wi,
    const int* __restrict__ ei,
    uint2* __restrict__ x2, uint2* __restrict__ pe2,
    bf16* __restrict__ Wl_pk, bf16* __restrict__ Wr_pk,
    bf16* __restrict__ Wp_pk, bf16* __restrict__ Wi_pk,
    int* __restrict__ ncnt, unsigned short* __restrict__ bped16) {
  const int b = blockIdx.x;
  const int t = threadIdx.x;
  if (b < SCAT) {
    const int chunk = b >> 3;
    const unsigned part = (unsigned)(b & 7);   // assumed XCD of this block
    const int e0 = chunk * BEPB;
    const int rem = min(BEPB, N_EDGES - e0);   // 2048, or 1280 for last chunk
    const bool va = (4 * t + 3 < rem);
    const bool vb = (1024 + 4 * t + 3 < rem);
    const int4* srcp = (const int4*)(ei + e0);
    const int4* dstp = (const int4*)(ei + N_EDGES + e0);
    auto scat = [&](int s, int d) {
      if (((unsigned)(d >> 6) & 7u) == part) {
        int pos = atomicAdd(&ncnt[d], 1);
        if (pos < NCAP)
          bped16[(size_t)d * NCAP + pos] = (unsigned short)s;
      }
    };
    if (va) {
      int4 sa = srcp[t], da = dstp[t];
      scat(sa.x, da.x); scat(sa.y, da.y); scat(sa.z, da.z); scat(sa.w, da.w);
    }
    if (vb) {
      int4 sb = srcp[256 + t], db = dstp[256 + t];
      scat(sb.x, db.x); scat(sb.y, db.y); scat(sb.z, db.z); scat(sb.w, db.w);
    }
    return;
  }
  const int pb = b - SCAT;
  if (pb < PREP_XC) {
    int tid = pb * 256 + t;
    float4 v = ((const float4*)x)[tid];
    x2[tid] = make_uint2(bf16rne(v.x) | (bf16rne(v.y) << 16),
                         bf16rne(v.z) | (bf16rne(v.w) << 16));
  } else if (pb < PREP_PE) {
    int tid = (pb - PREP_XC) * 256 + t;
    float4 v = ((const float4*)pe)[tid];
    pe2[tid] = make_uint2(bf16rne(v.x) | (bf16rne(v.y) << 16),
                          bf16rne(v.z) | (bf16rne(v.w) << 16));
  } else if (pb < PREP_PL) {
    pack_frag(Wl, Wl_pk, 2, (pb - PREP_PE) * 256 + t);
  } else if (pb < PREP_PR) {
    pack_frag(Wr, Wr_pk, 2, (pb - PREP_PL) * 256 + t);
  } else if (pb < PREP_WP) {
    pack_frag(Wp, Wp_pk, 40, (pb - PREP_PR) * 256 + t);
  } else {
    pack_frag(Wi, Wi_pk, 16, (pb - PREP_WP) * 256 + t);
  }
}

// ---------------------------------------------------------------------------
// K2 "mid": blockIdx [0,NB) = aggregation (R6 structure: no sort, runs are
// contiguous by construction; 2 barriers, zero LDS atomics). Stage the tile's
// 8KB run region (coalesced uint4, L2-local: same XCD that wrote it),
// register-gather, aggr tile -> MFMA MLP + bias + relu -> per-graph masked
// column sums into poolsum atomics.
// blockIdx [NB,NB+64) = protein GEMM, FULL K, writes bf16(acc+bp) protC.
// ---------------------------------------------------------------------------
__global__ __launch_bounds__(256, 4) void k_mid(
    const uint2* __restrict__ x2, const unsigned short* __restrict__ bped16,
    const int* __restrict__ ncnt, const int* __restrict__ batch,
    const bf16* __restrict__ Wl_pk, const bf16* __restrict__ Wr_pk,
    const float* __restrict__ bl, float* __restrict__ poolsum,
    const bf16* __restrict__ pebf, const bf16* __restrict__ Wp_pk,
    const float* __restrict__ bp, unsigned short* __restrict__ protC) {
  __shared__ uint2 aggT[64 * 18];            // 9216 B (144B rows: free 2-way)
  __shared__ unsigned short s_e[64 * NCAP];  // 8 KB edge runs
  __shared__ int s_cnt[64];
  __shared__ int s_batch[64];
  const int t = threadIdx.x;
  if (blockIdx.x < NB) {
    const int b = blockIdx.x;
    const int n0 = b * 64;
    if (t < 64) {
      s_cnt[t] = min(ncnt[n0 + t], NCAP);
      int node = n0 + t;
      s_batch[t] = (node < N_NODES) ? batch[node] : 0x7fffffff;
    }
    // stage the contiguous run region: 64 nodes x 64 u16 = 8KB, coalesced
    {
      const uint4* src = (const uint4*)(bped16 + (size_t)n0 * NCAP);
      uint4* dst = (uint4*)s_e;
      dst[t] = src[t];
      dst[256 + t] = src[256 + t];
    }
    __syncthreads();

    // per-node register gather: wave w handles nodes w, w+4, ...
    const int w = t >> 6, lane = t & 63;
    const int el = lane >> 4;      // edge slot (4 edges per step)
    const int fb = lane & 15;      // uint2 feature block
    for (int n = w; n < 64; n += 4) {
      const int beg = n * NCAP;
      const int cnt = s_cnt[n];
      const int end = beg + cnt;
      float4 s0 = {0,0,0,0}, s1 = {0,0,0,0}, s2 = {0,0,0,0}, s3 = {0,0,0,0};
      int e = beg;
      for (; e + 16 <= end; e += 16) {
        int i0 = s_e[e + el],     i1 = s_e[e + 4 + el];
        int i2 = s_e[e + 8 + el], i3 = s_e[e + 12 + el];
        uint2 v0 = x2[(size_t)i0 * 16 + fb];
        uint2 v1 = x2[(size_t)i1 * 16 + fb];
        uint2 v2 = x2[(size_t)i2 * 16 + fb];
        uint2 v3 = x2[(size_t)i3 * 16 + fb];
        acc_bf2(s0, v0); acc_bf2(s1, v1); acc_bf2(s2, v2); acc_bf2(s3, v3);
      }
      for (; e + 4 <= end; e += 4)
        acc_bf2(s0, x2[(size_t)s_e[e + el] * 16 + fb]);
      if (e + el < end)
        acc_bf2(s1, x2[(size_t)s_e[e + el] * 16 + fb]);
      float4 tt;
      tt.x = (s0.x + s1.x) + (s2.x + s3.x);
      tt.y = (s0.y + s1.y) + (s2.y + s3.y);
      tt.z = (s0.z + s1.z) + (s2.z + s3.z);
      tt.w = (s0.w + s1.w) + (s2.w + s3.w);
      tt.x += __shfl_xor(tt.x, 32); tt.x += __shfl_xor(tt.x, 16);
      tt.y += __shfl_xor(tt.y, 32); tt.y += __shfl_xor(tt.y, 16);
      tt.z += __shfl_xor(tt.z, 32); tt.z += __shfl_xor(tt.z, 16);
      tt.w += __shfl_xor(tt.w, 32); tt.w += __shfl_xor(tt.w, 16);
      if (el == 0) {
        float inv = 1.0f / (float)max(cnt, 1);
        uint2 o;
        o.x = bf16rne(tt.x * inv) | (bf16rne(tt.y * inv) << 16);
        o.y = bf16rne(tt.z * inv) | (bf16rne(tt.w * inv) << 16);
        aggT[n * 18 + fb] = o;    // rows with no edges write zeros
      }
    }
    __syncthreads();

    // fused MLP: relu(aggr@Wl + bl + x@Wr), per-rt acc reuse (16 VGPR)
    const int ml = lane & 15, q = lane >> 4;
    const int lv = min(63, N_NODES - 1 - n0);  // last valid local row
    float bic[4];
#pragma unroll
    for (int cl = 0; cl < 4; ++cl) bic[cl] = bl[w * 64 + cl * 16 + ml];
#pragma unroll
    for (int rt = 0; rt < 4; ++rt) {
      f32x4 acc[4];
#pragma unroll
      for (int cl = 0; cl < 4; ++cl) acc[cl] = (f32x4){0.f, 0.f, 0.f, 0.f};
      const int arow = rt * 16 + ml;
#pragma unroll
      for (int kc = 0; kc < 2; ++kc) {
        short8 a0 = *(const short8*)(&aggT[arow * 18 + kc * 8 + q * 2]);
#pragma unroll
        for (int cl = 0; cl < 4; ++cl) {
          short8 bb = *(const short8*)(Wl_pk + ((size_t)((w * 4 + cl) * 2 + kc) * 64 + lane) * 8);
          acc[cl] = __builtin_amdgcn_mfma_f32_16x16x32_bf16(a0, bb, acc[cl], 0, 0, 0);
        }
        short8 a1 = *(const short8*)((const bf16*)x2 + (size_t)(n0 + arow) * D_IN + kc * 32 + q * 8);
#pragma unroll
        for (int cl = 0; cl < 4; ++cl) {
          short8 bb = *(const short8*)(Wr_pk + ((size_t)((w * 4 + cl) * 2 + kc) * 64 + lane) * 8);
          acc[cl] = __builtin_amdgcn_mfma_f32_16x16x32_bf16(a1, bb, acc[cl], 0, 0, 0);
        }
      }
      // bias + relu, then per-graph masked column sums -> global atomics
      float vv[4][4];
      int bt[4];
#pragma unroll
      for (int i = 0; i < 4; ++i) bt[i] = s_batch[rt * 16 + q * 4 + i];
#pragma unroll
      for (int cl = 0; cl < 4; ++cl)
#pragma unroll
        for (int i = 0; i < 4; ++i)
          vv[cl][i] = fmaxf(acc[cl][i] + bic[cl], 0.f);
      const int glo = s_batch[min(rt * 16, lv)];
      const int ghi = s_batch[min(rt * 16 + 15, lv)];
      for (int g = glo; g <= ghi; ++g) {
#pragma unroll
        for (int cl = 0; cl < 4; ++cl) {
          float s = 0.f;
#pragma unroll
          for (int i = 0; i < 4; ++i) s += (bt[i] == g) ? vv[cl][i] : 0.f;
          s += __shfl_xor(s, 16); s += __shfl_xor(s, 32);
          if (q == 0)
            atomicAdd(&poolsum[(size_t)g * HID + (w * 64 + cl * 16 + ml)], s);
        }
      }
    }
    return;
  }
  // protein GEMM: pe[1024x1280] @ Wp[1280x256], FULL K, 64 blocks x 16 graphs
  const int kb = blockIdx.x - NB;     // 0..63
  const int w = t >> 6, lane = t & 63;
  const int ml = lane & 15, q = lane >> 4;
  const int g0 = kb * 16;
  f32x4 acc[4];
#pragma unroll
  for (int c = 0; c < 4; ++c) acc[c] = (f32x4){0.f, 0.f, 0.f, 0.f};
  for (int kc = 0; kc < 40; ++kc) {
    short8 a = *(const short8*)(pebf + (size_t)(g0 + ml) * D_PROT + kc * 32 + q * 8);
#pragma unroll
    for (int cl = 0; cl < 4; ++cl) {
      short8 bb = *(const short8*)(Wp_pk + ((size_t)((w * 4 + cl) * 40 + kc) * 64 + lane) * 8);
      acc[cl] = __builtin_amdgcn_mfma_f32_16x16x32_bf16(a, bb, acc[cl], 0, 0, 0);
    }
  }
#pragma unroll
  for (int cl = 0; cl < 4; ++cl) {
    const int col = w * 64 + cl * 16 + ml;
    const float bpc = bp[col];
#pragma unroll
    for (int i = 0; i < 4; ++i)
      protC[(size_t)(g0 + q * 4 + i) * HID + col] =
          (unsigned short)bf16rne(acc[cl][i] + bpc);
  }
}

// ---------------------------------------------------------------------------
// k_tail (FUSED finalize): 64 blocks x 16 graphs. Each block builds its own
// 16x512 bf16 A-tile in LDS (pooled mean from poolsum/counts || protC copy),
// then interaction MFMA + bias+relu+(*Wo)+column-reduce head.
// ---------------------------------------------------------------------------
__device__ inline int lb_dev(const int* __restrict__ a, int v) {
  int lo = 0, hi = N_NODES;
  while (lo < hi) { int m = (lo + hi) >> 1; if (a[m] < v) lo = m + 1; else hi = m; }
  return lo;
}

__global__ __launch_bounds__(256) void k_tail(
    const float* __restrict__ poolsum, const int* __restrict__ batch,
    const unsigned short* __restrict__ protC,
    const bf16* __restrict__ Wi_pk, const float* __restrict__ bi,
    const float* __restrict__ Wo, const float* __restrict__ bo,
    float* __restrict__ out) {
  __shared__ bf16 aT[16][520];   // +8 bf16 pad: 2-way (free) bank pattern
  __shared__ float s_inv[16];
  __shared__ float sRed[16 * 4];
  const int t = threadIdx.x, w = t >> 6, lane = t & 63;
  const int ml = lane & 15, q = lane >> 4;
  const int g0 = blockIdx.x * 16;
  if (t < 16) {
    int lo = lb_dev(batch, g0 + t), hi = lb_dev(batch, g0 + t + 1);
    s_inv[t] = 1.0f / (float)max(hi - lo, 1);
  }
  __syncthreads();
  // left half: pooled mean (f32 -> bf16); right half: direct bf16 copy
  for (int idx = t; idx < 16 * 256; idx += 256) {
    const int row = idx >> 8, col = idx & 255;
    float v = poolsum[(size_t)(g0 + row) * HID + col] * s_inv[row];
    ((unsigned short*)&aT[row][0])[col] = (unsigned short)bf16rne(v);
    ((unsigned short*)&aT[row][0])[HID + col] =
        protC[(size_t)(g0 + row) * HID + col];
  }
  __syncthreads();
  f32x4 acc[4];
#pragma unroll
  for (int c = 0; c < 4; ++c) acc[c] = (f32x4){0.f, 0.f, 0.f, 0.f};
  for (int kc = 0; kc < 16; ++kc) {
    short8 a = *(const short8*)(&aT[ml][kc * 32 + q * 8]);
#pragma unroll
    for (int cl = 0; cl < 4; ++cl) {
      short8 bb = *(const short8*)(Wi_pk + ((size_t)((w * 4 + cl) * 16 + kc) * 64 + lane) * 8);
      acc[cl] = __builtin_amdgcn_mfma_f32_16x16x32_bf16(a, bb, acc[cl], 0, 0, 0);
    }
  }
  // epilogue: inter = relu(acc + bi); partial = inter * Wo; reduce over cols
  float bic[4], woc[4];
#pragma unroll
  for (int cl = 0; cl < 4; ++cl) {
    const int col = w * 64 + cl * 16 + ml;
    bic[cl] = bi[col];
    woc[cl] = Wo[col];
  }
#pragma unroll
  for (int i = 0; i < 4; ++i) {
    float s = 0.f;
#pragma unroll
    for (int cl = 0; cl < 4; ++cl)
      s += fmaxf(acc[cl][i] + bic[cl], 0.f) * woc[cl];
    // reduce over the 16 ml lanes (stays within same q group)
    s += __shfl_xor(s, 1); s += __shfl_xor(s, 2);
    s += __shfl_xor(s, 4); s += __shfl_xor(s, 8);
    if (ml == 0) sRed[(q * 4 + i) * 4 + w] = s;
  }
  __syncthreads();
  if (t < 16)
    out[g0 + t] = sRed[t * 4 + 0] + sRed[t * 4 + 1] + sRed[t * 4 + 2]
                + sRed[t * 4 + 3] + bo[0];
}

extern "C" void kernel_launch(void* const* d_in, const int* in_sizes, int n_in,
                              void* d_out, int out_size, void* d_ws, size_t ws_size,
                              hipStream_t stream) {
  const float* x     = (const float*)d_in[0];
  const float* pe    = (const float*)d_in[1];
  const float* Wl    = (const float*)d_in[2];
  const float* bl    = (const float*)d_in[3];
  const float* Wr    = (const float*)d_in[4];
  const float* Wp    = (const float*)d_in[5];
  const float* bp    = (const float*)d_in[6];
  const float* Wi    = (const float*)d_in[7];
  const float* bi    = (const float*)d_in[8];
  const float* Wo    = (const float*)d_in[9];
  const float* bo    = (const float*)d_in[10];
  const int*   ei    = (const int*)d_in[11];
  const int*   batch = (const int*)d_in[12];
  float* out = (float*)d_out;

  char* p = (char*)d_ws;
  auto alloc = [&](size_t bytes) {
    char* r = p;
    p += (bytes + 255) & ~(size_t)255;
    return r;
  };
  int*   ncnt    = (int*)alloc((size_t)N_PAD * 4);          // 200 KB
  float* poolsum = (float*)alloc((size_t)N_GRAPHS * HID * 4);
  size_t zbytes = (size_t)(p - (char*)d_ws);   // ncnt + poolsum zeroed
  unsigned short* bped16 = (unsigned short*)alloc((size_t)N_PAD * NCAP * 2);
  bf16*  xbf    = (bf16*)alloc((size_t)N_PAD * D_IN * 2);
  bf16*  pebf   = (bf16*)alloc((size_t)N_GRAPHS * D_PROT * 2);
  bf16*  Wl_pk  = (bf16*)alloc((size_t)D_IN * HID * 2);
  bf16*  Wr_pk  = (bf16*)alloc((size_t)D_IN * HID * 2);
  bf16*  Wp_pk  = (bf16*)alloc((size_t)D_PROT * HID * 2);
  bf16*  Wi_pk  = (bf16*)alloc((size_t)2 * HID * HID * 2);
  unsigned short* protC = (unsigned short*)alloc((size_t)N_GRAPHS * HID * 2);

  (void)hipMemsetAsync(d_ws, 0, zbytes, stream);

  k_front<<<SCAT + PREP_WI, 256, 0, stream>>>(
      x, pe, Wl, Wr, Wp, Wi, ei,
      (uint2*)xbf, (uint2*)pebf, Wl_pk, Wr_pk, Wp_pk, Wi_pk, ncnt, bped16);
  k_mid<<<NB + 64, 256, 0, stream>>>(
      (const uint2*)xbf, bped16, ncnt, batch, Wl_pk, Wr_pk, bl, poolsum,
      pebf, Wp_pk, bp, protC);
  k_tail<<<N_GRAPHS / 16, 256, 0, stream>>>(
      poolsum, batch, protC, Wi_pk, bi, Wo, bo, out);
}

// Round 10
// 159.366 us; speedup vs baseline: 1.1318x; 1.1318x over previous
//
#include <hip/hip_runtime.h>
#include <hip/hip_bf16.h>

#define N_NODES 50000
#define N_EDGES 800000
#define N_GRAPHS 1024
#define D_IN 64
#define D_PROT 1280
#define HID 256
#define N_PAD 50048   // N_NODES padded to multiple of 64

// edge bucketing: 64 nodes per bucket
#define NB 782        // ceil(50048/64)
#define BCAP 2048     // capacity per bucket (mean 1023, max ~1200)
#define BEPB 2048     // edges per bucketing chunk
#define BBLK 391      // ceil(800000/2048); last chunk rem=1280 (mult of 4)

typedef __attribute__((ext_vector_type(8))) short short8;
typedef __attribute__((ext_vector_type(4))) float f32x4;
typedef __hip_bfloat16 bf16;

// round-to-nearest-even f32 -> bf16 bits (finite inputs only)
__device__ inline unsigned bf16rne(float f) {
  unsigned u = __float_as_uint(f);
  return (u + 0x7fffu + ((u >> 16) & 1u)) >> 16;
}
// accumulate 8 bf16 packed in uint4 into two float4s
__device__ inline void acc_bf4(float4& lo, float4& hi, uint4 v) {
  lo.x += __uint_as_float(v.x << 16);
  lo.y += __uint_as_float(v.x & 0xffff0000u);
  lo.z += __uint_as_float(v.y << 16);
  lo.w += __uint_as_float(v.y & 0xffff0000u);
  hi.x += __uint_as_float(v.z << 16);
  hi.y += __uint_as_float(v.z & 0xffff0000u);
  hi.z += __uint_as_float(v.w << 16);
  hi.w += __uint_as_float(v.w & 0xffff0000u);
}

// ---------------------------------------------------------------------------
// K1 "front": blockIdx [0,BBLK) = edge bucketing, single pass (8 edges per
// thread staged in registers via int4 loads) ∪ rest = conversions + packs.
// Identical to the 156us R4 version (best verified).
// ---------------------------------------------------------------------------
#define PREP_XC 3125                  // 50000*64/4 float4s / 256
#define PREP_PE (PREP_XC + 1280)      // 1024*1280/4 / 256
#define PREP_PL (PREP_PE + 8)         // Wl: 16 coltiles * 2 kc * 64 / 256
#define PREP_PR (PREP_PL + 8)         // Wr
#define PREP_WP (PREP_PR + 160)       // Wp: 16 * 40 * 64 / 256
#define PREP_WI (PREP_WP + 64)        // Wi: 16 * 16 * 64 / 256

__device__ inline void pack_frag(const float* __restrict__ src, bf16* __restrict__ dst,
                                 int KC, int tid) {
  int lane = tid & 63;
  int chunk = tid >> 6;            // = c*KC + kc
  int c = chunk / KC, kc = chunk - c * KC;
  int kbase = kc * 32 + ((lane >> 4) * 8);
  int n = c * 16 + (lane & 15);
#pragma unroll
  for (int j = 0; j < 8; ++j)
    dst[(size_t)tid * 8 + j] = __float2bfloat16(src[(size_t)(kbase + j) * HID + n]);
}

__global__ __launch_bounds__(256) void k_front(
    const float* __restrict__ x, const float* __restrict__ pe,
    const float* __restrict__ Wl, const float* __restrict__ Wr,
    const float* __restrict__ Wp, const float* __restrict__ Wi,
    const int* __restrict__ ei,
    uint2* __restrict__ x2, uint2* __restrict__ pe2,
    bf16* __restrict__ Wl_pk, bf16* __restrict__ Wr_pk,
    bf16* __restrict__ Wp_pk, bf16* __restrict__ Wi_pk,
    int* __restrict__ bcnt, unsigned* __restrict__ bped) {
  __shared__ int hist[NB];
  __shared__ int base[NB];
  const int b = blockIdx.x;
  const int t = threadIdx.x;
  if (b < BBLK) {
    const int e0 = b * BEPB;
    for (int i = t; i < NB; i += 256) hist[i] = 0;
    // single load phase: edges e0+4t..4t+3 and e0+1024+4t..+3 (int4 pairs)
    const int rem = min(BEPB, N_EDGES - e0);   // 2048, or 1280 for last chunk
    const bool va = (4 * t + 3 < rem);
    const bool vb = (1024 + 4 * t + 3 < rem);
    const int4* srcp = (const int4*)(ei + e0);
    const int4* dstp = (const int4*)(ei + N_EDGES + e0);
    int4 sa = {0,0,0,0}, sb = {0,0,0,0}, da = {0,0,0,0}, db = {0,0,0,0};
    if (va) { sa = srcp[t];       da = dstp[t]; }
    if (vb) { sb = srcp[256 + t]; db = dstp[256 + t]; }
    __syncthreads();
    if (va) {
      atomicAdd(&hist[da.x >> 6], 1); atomicAdd(&hist[da.y >> 6], 1);
      atomicAdd(&hist[da.z >> 6], 1); atomicAdd(&hist[da.w >> 6], 1);
    }
    if (vb) {
      atomicAdd(&hist[db.x >> 6], 1); atomicAdd(&hist[db.y >> 6], 1);
      atomicAdd(&hist[db.z >> 6], 1); atomicAdd(&hist[db.w >> 6], 1);
    }
    __syncthreads();
    // reservation: ONE global atomic per (block,bucket)
    for (int i = t; i < NB; i += 256) {
      int c = hist[i];
      base[i] = (c > 0) ? atomicAdd(&bcnt[i], c) : 0;
      hist[i] = 0;  // reuse as local cursor
    }
    __syncthreads();
    // scatter from registers: packed src|(local)<<16 into contiguous runs
    auto scat = [&](int s, int d) {
      int bk = d >> 6;
      int pos = base[bk] + atomicAdd(&hist[bk], 1);
      if (pos < BCAP)
        bped[(size_t)bk * BCAP + pos] =
            (unsigned)s | ((unsigned)(d & 63) << 16);
    };
    if (va) { scat(sa.x, da.x); scat(sa.y, da.y); scat(sa.z, da.z); scat(sa.w, da.w); }
    if (vb) { scat(sb.x, db.x); scat(sb.y, db.y); scat(sb.z, db.z); scat(sb.w, db.w); }
    return;
  }
  const int pb = b - BBLK;
  if (pb < PREP_XC) {
    int tid = pb * 256 + t;
    float4 v = ((const float4*)x)[tid];
    x2[tid] = make_uint2(bf16rne(v.x) | (bf16rne(v.y) << 16),
                         bf16rne(v.z) | (bf16rne(v.w) << 16));
  } else if (pb < PREP_PE) {
    int tid = (pb - PREP_XC) * 256 + t;
    float4 v = ((const float4*)pe)[tid];
    pe2[tid] = make_uint2(bf16rne(v.x) | (bf16rne(v.y) << 16),
                          bf16rne(v.z) | (bf16rne(v.w) << 16));
  } else if (pb < PREP_PL) {
    pack_frag(Wl, Wl_pk, 2, (pb - PREP_PE) * 256 + t);
  } else if (pb < PREP_PR) {
    pack_frag(Wr, Wr_pk, 2, (pb - PREP_PL) * 256 + t);
  } else if (pb < PREP_WP) {
    pack_frag(Wp, Wp_pk, 40, (pb - PREP_PR) * 256 + t);
  } else {
    pack_frag(Wi, Wi_pk, 16, (pb - PREP_WP) * 256 + t);
  }
}

// ---------------------------------------------------------------------------
// K2 "mid": blockIdx [0,NB) = aggregation (R4 counting-sort structure) with
// WIDENED GATHER: uint4 (16B/lane) loads -> 8 edges per wave-instruction
// (was uint2/4 edges). Halves the latency-bound gather instruction count,
// doubles bytes-in-flight per wave at the 25%-occupancy latency floor.
// blockIdx [NB,NB+64) = protein GEMM, FULL K, writes bf16(acc+bp) protC.
// ---------------------------------------------------------------------------
__global__ __launch_bounds__(256, 4) void k_mid(
    const uint2* __restrict__ x2, const unsigned* __restrict__ bped,
    const int* __restrict__ bcnt, const int* __restrict__ batch,
    const bf16* __restrict__ Wl_pk, const bf16* __restrict__ Wr_pk,
    const float* __restrict__ bl, float* __restrict__ poolsum,
    const bf16* __restrict__ pebf, const bf16* __restrict__ Wp_pk,
    const float* __restrict__ bp, unsigned short* __restrict__ protC) {
  // s_raw (sort scratch) aliases aggT (64x18 uint2 rows of 144B: free 2-way,
  // 16B-aligned row stride for uint4 writes)
  __shared__ unsigned s_raw[2304];      // 9216 B
  __shared__ unsigned short s_e[BCAP];  // 4 KB
  __shared__ int s_off[65];
  __shared__ int s_cur[64];
  __shared__ int s_batch[64];
  const int t = threadIdx.x;
  if (blockIdx.x < NB) {
    uint2* aggT = (uint2*)s_raw;
    const int b = blockIdx.x;
    const int n0 = b * 64;
    const int nE = min(bcnt[b], BCAP);
    if (t < 64) s_cur[t] = 0;
    __syncthreads();
    for (int i = t; i < nE; i += 256) {
      unsigned pk = bped[(size_t)b * BCAP + i];
      s_raw[i] = pk;
      atomicAdd(&s_cur[(pk >> 16) & 63], 1);
    }
    __syncthreads();
    if (t < 64) {
      int sc = s_cur[t];
#pragma unroll
      for (int off = 1; off < 64; off <<= 1) {
        int u = __shfl_up(sc, off);
        if (t >= off) sc += u;
      }
      s_off[t + 1] = sc;
      if (t == 0) s_off[0] = 0;
      s_cur[t] = 0;
    }
    __syncthreads();
    for (int i = t; i < nE; i += 256) {
      unsigned pk = s_raw[i];
      int ld = (pk >> 16) & 63;
      int pos = s_off[ld] + atomicAdd(&s_cur[ld], 1);
      s_e[pos] = (unsigned short)(pk & 0xffffu);
    }
    if (t < 64) {
      int node = n0 + t;
      s_batch[t] = (node < N_NODES) ? batch[node] : 0x7fffffff;
    }
    __syncthreads();   // s_raw dead from here on -> aggT may be written

    // per-node register gather, 16B/lane: wave w handles nodes w, w+4, ...
    const uint4* x4 = (const uint4*)x2;
    const int w = t >> 6, lane = t & 63;
    const int el = lane >> 3;      // edge slot (8 edges per step)
    const int fb = lane & 7;       // uint4 feature block (16B of the 128B row)
    for (int n = w; n < 64; n += 4) {
      const int beg = s_off[n], end = s_off[n + 1];
      float4 a0 = {0,0,0,0}, a1 = {0,0,0,0};   // acc for slot stream A
      float4 b0 = {0,0,0,0}, b1 = {0,0,0,0};   // acc for slot stream B
      int e = beg;
      for (; e + 16 <= end; e += 16) {         // 16 edges: 2 loads in flight
        int i0 = s_e[e + el], i1 = s_e[e + 8 + el];
        uint4 v0 = x4[(size_t)i0 * 8 + fb];
        uint4 v1 = x4[(size_t)i1 * 8 + fb];
        acc_bf4(a0, a1, v0); acc_bf4(b0, b1, v1);
      }
      for (; e + 8 <= end; e += 8)
        acc_bf4(a0, a1, x4[(size_t)s_e[e + el] * 8 + fb]);
      if (e + el < end)
        acc_bf4(b0, b1, x4[(size_t)s_e[e + el] * 8 + fb]);
      float4 t0, t1;
      t0.x = a0.x + b0.x; t0.y = a0.y + b0.y;
      t0.z = a0.z + b0.z; t0.w = a0.w + b0.w;
      t1.x = a1.x + b1.x; t1.y = a1.y + b1.y;
      t1.z = a1.z + b1.z; t1.w = a1.w + b1.w;
      // reduce across the 8 edge-slot groups (lane bits 3..5)
      t0.x += __shfl_xor(t0.x, 8); t0.x += __shfl_xor(t0.x, 16); t0.x += __shfl_xor(t0.x, 32);
      t0.y += __shfl_xor(t0.y, 8); t0.y += __shfl_xor(t0.y, 16); t0.y += __shfl_xor(t0.y, 32);
      t0.z += __shfl_xor(t0.z, 8); t0.z += __shfl_xor(t0.z, 16); t0.z += __shfl_xor(t0.z, 32);
      t0.w += __shfl_xor(t0.w, 8); t0.w += __shfl_xor(t0.w, 16); t0.w += __shfl_xor(t0.w, 32);
      t1.x += __shfl_xor(t1.x, 8); t1.x += __shfl_xor(t1.x, 16); t1.x += __shfl_xor(t1.x, 32);
      t1.y += __shfl_xor(t1.y, 8); t1.y += __shfl_xor(t1.y, 16); t1.y += __shfl_xor(t1.y, 32);
      t1.z += __shfl_xor(t1.z, 8); t1.z += __shfl_xor(t1.z, 16); t1.z += __shfl_xor(t1.z, 32);
      t1.w += __shfl_xor(t1.w, 8); t1.w += __shfl_xor(t1.w, 16); t1.w += __shfl_xor(t1.w, 32);
      if (el == 0) {
        float inv = 1.0f / (float)max(end - beg, 1);
        uint4 o;
        o.x = bf16rne(t0.x * inv) | (bf16rne(t0.y * inv) << 16);
        o.y = bf16rne(t0.z * inv) | (bf16rne(t0.w * inv) << 16);
        o.z = bf16rne(t1.x * inv) | (bf16rne(t1.y * inv) << 16);
        o.w = bf16rne(t1.z * inv) | (bf16rne(t1.w * inv) << 16);
        ((uint4*)aggT)[n * 9 + fb] = o;   // 144B rows: 9 uint4 per node
      }
    }
    __syncthreads();

    // fused MLP: relu(aggr@Wl + bl + x@Wr), per-rt acc reuse (16 VGPR)
    const int ml = lane & 15, q = lane >> 4;
    const int lv = min(63, N_NODES - 1 - n0);  // last valid local row
    float bic[4];
#pragma unroll
    for (int cl = 0; cl < 4; ++cl) bic[cl] = bl[w * 64 + cl * 16 + ml];
#pragma unroll
    for (int rt = 0; rt < 4; ++rt) {
      f32x4 acc[4];
#pragma unroll
      for (int cl = 0; cl < 4; ++cl) acc[cl] = (f32x4){0.f, 0.f, 0.f, 0.f};
      const int arow = rt * 16 + ml;
#pragma unroll
      for (int kc = 0; kc < 2; ++kc) {
        short8 a0 = *(const short8*)(&aggT[arow * 18 + kc * 8 + q * 2]);
#pragma unroll
        for (int cl = 0; cl < 4; ++cl) {
          short8 bb = *(const short8*)(Wl_pk + ((size_t)((w * 4 + cl) * 2 + kc) * 64 + lane) * 8);
          acc[cl] = __builtin_amdgcn_mfma_f32_16x16x32_bf16(a0, bb, acc[cl], 0, 0, 0);
        }
        short8 a1 = *(const short8*)((const bf16*)x2 + (size_t)(n0 + arow) * D_IN + kc * 32 + q * 8);
#pragma unroll
        for (int cl = 0; cl < 4; ++cl) {
          short8 bb = *(const short8*)(Wr_pk + ((size_t)((w * 4 + cl) * 2 + kc) * 64 + lane) * 8);
          acc[cl] = __builtin_amdgcn_mfma_f32_16x16x32_bf16(a1, bb, acc[cl], 0, 0, 0);
        }
      }
      // bias + relu, then per-graph masked column sums -> global atomics
      float vv[4][4];
      int bt[4];
#pragma unroll
      for (int i = 0; i < 4; ++i) bt[i] = s_batch[rt * 16 + q * 4 + i];
#pragma unroll
      for (int cl = 0; cl < 4; ++cl)
#pragma unroll
        for (int i = 0; i < 4; ++i)
          vv[cl][i] = fmaxf(acc[cl][i] + bic[cl], 0.f);
      const int glo = s_batch[min(rt * 16, lv)];
      const int ghi = s_batch[min(rt * 16 + 15, lv)];
      for (int g = glo; g <= ghi; ++g) {
#pragma unroll
        for (int cl = 0; cl < 4; ++cl) {
          float s = 0.f;
#pragma unroll
          for (int i = 0; i < 4; ++i) s += (bt[i] == g) ? vv[cl][i] : 0.f;
          s += __shfl_xor(s, 16); s += __shfl_xor(s, 32);
          if (q == 0)
            atomicAdd(&poolsum[(size_t)g * HID + (w * 64 + cl * 16 + ml)], s);
        }
      }
    }
    return;
  }
  // protein GEMM: pe[1024x1280] @ Wp[1280x256], FULL K, 64 blocks x 16 graphs
  const int kb = blockIdx.x - NB;     // 0..63
  const int w = t >> 6, lane = t & 63;
  const int ml = lane & 15, q = lane >> 4;
  const int g0 = kb * 16;
  f32x4 acc[4];
#pragma unroll
  for (int c = 0; c < 4; ++c) acc[c] = (f32x4){0.f, 0.f, 0.f, 0.f};
  for (int kc = 0; kc < 40; ++kc) {
    short8 a = *(const short8*)(pebf + (size_t)(g0 + ml) * D_PROT + kc * 32 + q * 8);
#pragma unroll
    for (int cl = 0; cl < 4; ++cl) {
      short8 bb = *(const short8*)(Wp_pk + ((size_t)((w * 4 + cl) * 40 + kc) * 64 + lane) * 8);
      acc[cl] = __builtin_amdgcn_mfma_f32_16x16x32_bf16(a, bb, acc[cl], 0, 0, 0);
    }
  }
#pragma unroll
  for (int cl = 0; cl < 4; ++cl) {
    const int col = w * 64 + cl * 16 + ml;
    const float bpc = bp[col];
#pragma unroll
    for (int i = 0; i < 4; ++i)
      protC[(size_t)(g0 + q * 4 + i) * HID + col] =
          (unsigned short)bf16rne(acc[cl][i] + bpc);
  }
}

// ---------------------------------------------------------------------------
// k_tail (FUSED finalize): 64 blocks x 16 graphs. Each block builds its own
// 16x512 bf16 A-tile in LDS (pooled mean from poolsum/counts || protC copy),
// then interaction MFMA + bias+relu+(*Wo)+column-reduce head.
// ---------------------------------------------------------------------------
__device__ inline int lb_dev(const int* __restrict__ a, int v) {
  int lo = 0, hi = N_NODES;
  while (lo < hi) { int m = (lo + hi) >> 1; if (a[m] < v) lo = m + 1; else hi = m; }
  return lo;
}

__global__ __launch_bounds__(256) void k_tail(
    const float* __restrict__ poolsum, const int* __restrict__ batch,
    const unsigned short* __restrict__ protC,
    const bf16* __restrict__ Wi_pk, const float* __restrict__ bi,
    const float* __restrict__ Wo, const float* __restrict__ bo,
    float* __restrict__ out) {
  __shared__ bf16 aT[16][520];   // +8 bf16 pad: 2-way (free) bank pattern
  __shared__ float s_inv[16];
  __shared__ float sRed[16 * 4];
  const int t = threadIdx.x, w = t >> 6, lane = t & 63;
  const int ml = lane & 15, q = lane >> 4;
  const int g0 = blockIdx.x * 16;
  if (t < 16) {
    int lo = lb_dev(batch, g0 + t), hi = lb_dev(batch, g0 + t + 1);
    s_inv[t] = 1.0f / (float)max(hi - lo, 1);
  }
  __syncthreads();
  // left half: pooled mean (f32 -> bf16); right half: direct bf16 copy
  for (int idx = t; idx < 16 * 256; idx += 256) {
    const int row = idx >> 8, col = idx & 255;
    float v = poolsum[(size_t)(g0 + row) * HID + col] * s_inv[row];
    ((unsigned short*)&aT[row][0])[col] = (unsigned short)bf16rne(v);
    ((unsigned short*)&aT[row][0])[HID + col] =
        protC[(size_t)(g0 + row) * HID + col];
  }
  __syncthreads();
  f32x4 acc[4];
#pragma unroll
  for (int c = 0; c < 4; ++c) acc[c] = (f32x4){0.f, 0.f, 0.f, 0.f};
  for (int kc = 0; kc < 16; ++kc) {
    short8 a = *(const short8*)(&aT[ml][kc * 32 + q * 8]);
#pragma unroll
    for (int cl = 0; cl < 4; ++cl) {
      short8 bb = *(const short8*)(Wi_pk + ((size_t)((w * 4 + cl) * 16 + kc) * 64 + lane) * 8);
      acc[cl] = __builtin_amdgcn_mfma_f32_16x16x32_bf16(a, bb, acc[cl], 0, 0, 0);
    }
  }
  // epilogue: inter = relu(acc + bi); partial = inter * Wo; reduce over cols
  float bic[4], woc[4];
#pragma unroll
  for (int cl = 0; cl < 4; ++cl) {
    const int col = w * 64 + cl * 16 + ml;
    bic[cl] = bi[col];
    woc[cl] = Wo[col];
  }
#pragma unroll
  for (int i = 0; i < 4; ++i) {
    float s = 0.f;
#pragma unroll
    for (int cl = 0; cl < 4; ++cl)
      s += fmaxf(acc[cl][i] + bic[cl], 0.f) * woc[cl];
    // reduce over the 16 ml lanes (stays within same q group)
    s += __shfl_xor(s, 1); s += __shfl_xor(s, 2);
    s += __shfl_xor(s, 4); s += __shfl_xor(s, 8);
    if (ml == 0) sRed[(q * 4 + i) * 4 + w] = s;
  }
  __syncthreads();
  if (t < 16)
    out[g0 + t] = sRed[t * 4 + 0] + sRed[t * 4 + 1] + sRed[t * 4 + 2]
                + sRed[t * 4 + 3] + bo[0];
}

extern "C" void kernel_launch(void* const* d_in, const int* in_sizes, int n_in,
                              void* d_out, int out_size, void* d_ws, size_t ws_size,
                              hipStream_t stream) {
  const float* x     = (const float*)d_in[0];
  const float* pe    = (const float*)d_in[1];
  const float* Wl    = (const float*)d_in[2];
  const float* bl    = (const float*)d_in[3];
  const float* Wr    = (const float*)d_in[4];
  const float* Wp    = (const float*)d_in[5];
  const float* bp    = (const float*)d_in[6];
  const float* Wi    = (const float*)d_in[7];
  const float* bi    = (const float*)d_in[8];
  const float* Wo    = (const float*)d_in[9];
  const float* bo    = (const float*)d_in[10];
  const int*   ei    = (const int*)d_in[11];
  const int*   batch = (const int*)d_in[12];
  float* out = (float*)d_out;

  char* p = (char*)d_ws;
  auto alloc = [&](size_t bytes) {
    char* r = p;
    p += (bytes + 255) & ~(size_t)255;
    return r;
  };
  int*   bcnt    = (int*)alloc(NB * 4);
  float* poolsum = (float*)alloc((size_t)N_GRAPHS * HID * 4);
  size_t zbytes = (size_t)(p - (char*)d_ws);   // bcnt + poolsum zeroed
  unsigned* bped  = (unsigned*)alloc((size_t)NB * BCAP * 4);
  bf16*  xbf    = (bf16*)alloc((size_t)N_PAD * D_IN * 2);
  bf16*  pebf   = (bf16*)alloc((size_t)N_GRAPHS * D_PROT * 2);
  bf16*  Wl_pk  = (bf16*)alloc((size_t)D_IN * HID * 2);
  bf16*  Wr_pk  = (bf16*)alloc((size_t)D_IN * HID * 2);
  bf16*  Wp_pk  = (bf16*)alloc((size_t)D_PROT * HID * 2);
  bf16*  Wi_pk  = (bf16*)alloc((size_t)2 * HID * HID * 2);
  unsigned short* protC = (unsigned short*)alloc((size_t)N_GRAPHS * HID * 2);

  (void)hipMemsetAsync(d_ws, 0, zbytes, stream);

  k_front<<<BBLK + PREP_WI, 256, 0, stream>>>(
      x, pe, Wl, Wr, Wp, Wi, ei,
      (uint2*)xbf, (uint2*)pebf, Wl_pk, Wr_pk, Wp_pk, Wi_pk, bcnt, bped);
  k_mid<<<NB + 64, 256, 0, stream>>>(
      (const uint2*)xbf, bped, bcnt, batch, Wl_pk, Wr_pk, bl, poolsum,
      pebf, Wp_pk, bp, protC);
  k_tail<<<N_GRAPHS / 16, 256, 0, stream>>>(
      poolsum, batch, protC, Wi_pk, bi, Wo, bo, out);
}

// Round 11
// 155.213 us; speedup vs baseline: 1.1621x; 1.0268x over previous
//
#include <hip/hip_runtime.h>
#include <hip/hip_bf16.h>

#define N_NODES 50000
#define N_EDGES 800000
#define N_GRAPHS 1024
#define D_IN 64
#define D_PROT 1280
#define HID 256
#define N_PAD 50048   // N_NODES padded to multiple of 64

// edge bucketing: 64 nodes per bucket
#define NB 782        // ceil(50048/64)
#define BCAP 2048     // capacity per bucket (mean 1023, max ~1200)
#define BEPB 8192     // edges per bucketing chunk (big: 98x782 = 77K reservation
                      // atomics, was 285K at 2048 — global-atomic count is the
                      // measured lever: R6's 800K-atomic variant = 48us @1.5TB/s)
#define BBLK 98       // ceil(800000/8192); last chunk rem=5376 (mult of 4)

typedef __attribute__((ext_vector_type(8))) short short8;
typedef __attribute__((ext_vector_type(4))) float f32x4;
typedef __hip_bfloat16 bf16;

// round-to-nearest-even f32 -> bf16 bits (finite inputs only)
__device__ inline unsigned bf16rne(float f) {
  unsigned u = __float_as_uint(f);
  return (u + 0x7fffu + ((u >> 16) & 1u)) >> 16;
}
// accumulate 4 bf16 packed in uint2 into float4
__device__ inline void acc_bf2(float4& a, uint2 v) {
  a.x += __uint_as_float(v.x << 16);
  a.y += __uint_as_float(v.x & 0xffff0000u);
  a.z += __uint_as_float(v.y << 16);
  a.w += __uint_as_float(v.y & 0xffff0000u);
}

// ---------------------------------------------------------------------------
// K1 "front": blockIdx [0,BBLK) = edge bucketing. 32 edges/thread: dst staged
// in 8 int4 registers (histogram + scatter), src loaded once at scatter.
// ei read exactly once. ∪ rest = conversions + weight packing (BW-bound).
// ---------------------------------------------------------------------------
#define PREP_XC 3125                  // 50000*64/4 float4s / 256
#define PREP_PE (PREP_XC + 1280)      // 1024*1280/4 / 256
#define PREP_PL (PREP_PE + 8)         // Wl: 16 coltiles * 2 kc * 64 / 256
#define PREP_PR (PREP_PL + 8)         // Wr
#define PREP_WP (PREP_PR + 160)       // Wp: 16 * 40 * 64 / 256
#define PREP_WI (PREP_WP + 64)        // Wi: 16 * 16 * 64 / 256

__device__ inline void pack_frag(const float* __restrict__ src, bf16* __restrict__ dst,
                                 int KC, int tid) {
  int lane = tid & 63;
  int chunk = tid >> 6;            // = c*KC + kc
  int c = chunk / KC, kc = chunk - c * KC;
  int kbase = kc * 32 + ((lane >> 4) * 8);
  int n = c * 16 + (lane & 15);
#pragma unroll
  for (int j = 0; j < 8; ++j)
    dst[(size_t)tid * 8 + j] = __float2bfloat16(src[(size_t)(kbase + j) * HID + n]);
}

__global__ __launch_bounds__(256) void k_front(
    const float* __restrict__ x, const float* __restrict__ pe,
    const float* __restrict__ Wl, const float* __restrict__ Wr,
    const float* __restrict__ Wp, const float* __restrict__ Wi,
    const int* __restrict__ ei,
    uint2* __restrict__ x2, uint2* __restrict__ pe2,
    bf16* __restrict__ Wl_pk, bf16* __restrict__ Wr_pk,
    bf16* __restrict__ Wp_pk, bf16* __restrict__ Wi_pk,
    int* __restrict__ bcnt, unsigned* __restrict__ bped) {
  __shared__ int hist[NB];
  __shared__ int base[NB];
  const int b = blockIdx.x;
  const int t = threadIdx.x;
  if (b < BBLK) {
    const int e0 = b * BEPB;
    for (int i = t; i < NB; i += 256) hist[i] = 0;
    const int rem = min(BEPB, N_EDGES - e0);   // 8192, or 5376 for last chunk
    const int4* srcp = (const int4*)(ei + e0);
    const int4* dstp = (const int4*)(ei + N_EDGES + e0);
    int4 d[8]; bool v[8];
#pragma unroll
    for (int g = 0; g < 8; ++g) {
      const int i4 = g * 256 + t;
      v[g] = (4 * i4 + 3 < rem);
      d[g] = v[g] ? dstp[i4] : make_int4(0, 0, 0, 0);
    }
    __syncthreads();
#pragma unroll
    for (int g = 0; g < 8; ++g) {
      if (v[g]) {
        atomicAdd(&hist[d[g].x >> 6], 1); atomicAdd(&hist[d[g].y >> 6], 1);
        atomicAdd(&hist[d[g].z >> 6], 1); atomicAdd(&hist[d[g].w >> 6], 1);
      }
    }
    __syncthreads();
    // reservation: ONE global atomic per (block,bucket) -> 77K total
    for (int i = t; i < NB; i += 256) {
      int c = hist[i];
      base[i] = (c > 0) ? atomicAdd(&bcnt[i], c) : 0;
      hist[i] = 0;  // reuse as local cursor
    }
    __syncthreads();
    // scatter: src loaded fresh (coalesced), dst from registers
    auto scat = [&](int s, int dd) {
      int bk = dd >> 6;
      int pos = base[bk] + atomicAdd(&hist[bk], 1);
      if (pos < BCAP)
        bped[(size_t)bk * BCAP + pos] =
            (unsigned)s | ((unsigned)(dd & 63) << 16);
    };
#pragma unroll
    for (int g = 0; g < 8; ++g) {
      if (v[g]) {
        int4 s = srcp[g * 256 + t];
        scat(s.x, d[g].x); scat(s.y, d[g].y);
        scat(s.z, d[g].z); scat(s.w, d[g].w);
      }
    }
    return;
  }
  const int pb = b - BBLK;
  if (pb < PREP_XC) {
    int tid = pb * 256 + t;
    float4 v = ((const float4*)x)[tid];
    x2[tid] = make_uint2(bf16rne(v.x) | (bf16rne(v.y) << 16),
                         bf16rne(v.z) | (bf16rne(v.w) << 16));
  } else if (pb < PREP_PE) {
    int tid = (pb - PREP_XC) * 256 + t;
    float4 v = ((const float4*)pe)[tid];
    pe2[tid] = make_uint2(bf16rne(v.x) | (bf16rne(v.y) << 16),
                          bf16rne(v.z) | (bf16rne(v.w) << 16));
  } else if (pb < PREP_PL) {
    pack_frag(Wl, Wl_pk, 2, (pb - PREP_PE) * 256 + t);
  } else if (pb < PREP_PR) {
    pack_frag(Wr, Wr_pk, 2, (pb - PREP_PL) * 256 + t);
  } else if (pb < PREP_WP) {
    pack_frag(Wp, Wp_pk, 40, (pb - PREP_PR) * 256 + t);
  } else {
    pack_frag(Wi, Wi_pk, 16, (pb - PREP_WP) * 256 + t);
  }
}

// ---------------------------------------------------------------------------
// K2 "mid" (exact R4 = best-verified): blockIdx [0,NB) = aggregation
// (counting-sort in LDS + uint2 register gather) -> aggr tile in LDS -> MFMA
// MLP + bias + relu -> per-graph masked column sums (poolsum atomics).
// blockIdx [NB,NB+64) = protein GEMM, FULL K, writes bf16(acc+bp) protC.
// ---------------------------------------------------------------------------
__global__ __launch_bounds__(256, 4) void k_mid(
    const uint2* __restrict__ x2, const unsigned* __restrict__ bped,
    const int* __restrict__ bcnt, const int* __restrict__ batch,
    const bf16* __restrict__ Wl_pk, const bf16* __restrict__ Wr_pk,
    const float* __restrict__ bl, float* __restrict__ poolsum,
    const bf16* __restrict__ pebf, const bf16* __restrict__ Wp_pk,
    const float* __restrict__ bp, unsigned short* __restrict__ protC) {
  // s_raw (sort scratch) aliases aggT (64x18 uint2 rows of 144B: free 2-way)
  __shared__ unsigned s_raw[2304];      // 9216 B
  __shared__ unsigned short s_e[BCAP];  // 4 KB
  __shared__ int s_off[65];
  __shared__ int s_cur[64];
  __shared__ int s_batch[64];
  const int t = threadIdx.x;
  if (blockIdx.x < NB) {
    uint2* aggT = (uint2*)s_raw;
    const int b = blockIdx.x;
    const int n0 = b * 64;
    const int nE = min(bcnt[b], BCAP);
    if (t < 64) s_cur[t] = 0;
    __syncthreads();
    for (int i = t; i < nE; i += 256) {
      unsigned pk = bped[(size_t)b * BCAP + i];
      s_raw[i] = pk;
      atomicAdd(&s_cur[(pk >> 16) & 63], 1);
    }
    __syncthreads();
    if (t < 64) {
      int sc = s_cur[t];
#pragma unroll
      for (int off = 1; off < 64; off <<= 1) {
        int u = __shfl_up(sc, off);
        if (t >= off) sc += u;
      }
      s_off[t + 1] = sc;
      if (t == 0) s_off[0] = 0;
      s_cur[t] = 0;
    }
    __syncthreads();
    for (int i = t; i < nE; i += 256) {
      unsigned pk = s_raw[i];
      int ld = (pk >> 16) & 63;
      int pos = s_off[ld] + atomicAdd(&s_cur[ld], 1);
      s_e[pos] = (unsigned short)(pk & 0xffffu);
    }
    if (t < 64) {
      int node = n0 + t;
      s_batch[t] = (node < N_NODES) ? batch[node] : 0x7fffffff;
    }
    __syncthreads();   // s_raw dead from here on -> aggT may be written

    // per-node register gather: wave w handles nodes w, w+4, ...
    const int w = t >> 6, lane = t & 63;
    const int el = lane >> 4;      // edge slot (4 edges per step)
    const int fb = lane & 15;      // uint2 feature block
    for (int n = w; n < 64; n += 4) {
      const int beg = s_off[n], end = s_off[n + 1];
      float4 s0 = {0,0,0,0}, s1 = {0,0,0,0}, s2 = {0,0,0,0}, s3 = {0,0,0,0};
      int e = beg;
      for (; e + 16 <= end; e += 16) {
        int i0 = s_e[e + el],     i1 = s_e[e + 4 + el];
        int i2 = s_e[e + 8 + el], i3 = s_e[e + 12 + el];
        uint2 v0 = x2[(size_t)i0 * 16 + fb];
        uint2 v1 = x2[(size_t)i1 * 16 + fb];
        uint2 v2 = x2[(size_t)i2 * 16 + fb];
        uint2 v3 = x2[(size_t)i3 * 16 + fb];
        acc_bf2(s0, v0); acc_bf2(s1, v1); acc_bf2(s2, v2); acc_bf2(s3, v3);
      }
      for (; e + 4 <= end; e += 4)
        acc_bf2(s0, x2[(size_t)s_e[e + el] * 16 + fb]);
      if (e + el < end)
        acc_bf2(s1, x2[(size_t)s_e[e + el] * 16 + fb]);
      float4 tt;
      tt.x = (s0.x + s1.x) + (s2.x + s3.x);
      tt.y = (s0.y + s1.y) + (s2.y + s3.y);
      tt.z = (s0.z + s1.z) + (s2.z + s3.z);
      tt.w = (s0.w + s1.w) + (s2.w + s3.w);
      tt.x += __shfl_xor(tt.x, 32); tt.x += __shfl_xor(tt.x, 16);
      tt.y += __shfl_xor(tt.y, 32); tt.y += __shfl_xor(tt.y, 16);
      tt.z += __shfl_xor(tt.z, 32); tt.z += __shfl_xor(tt.z, 16);
      tt.w += __shfl_xor(tt.w, 32); tt.w += __shfl_xor(tt.w, 16);
      if (el == 0) {
        float inv = 1.0f / (float)max(end - beg, 1);
        uint2 o;
        o.x = bf16rne(tt.x * inv) | (bf16rne(tt.y * inv) << 16);
        o.y = bf16rne(tt.z * inv) | (bf16rne(tt.w * inv) << 16);
        aggT[n * 18 + fb] = o;    // rows with no edges write zeros
      }
    }
    __syncthreads();

    // fused MLP: relu(aggr@Wl + bl + x@Wr), per-rt acc reuse (16 VGPR)
    const int ml = lane & 15, q = lane >> 4;
    const int lv = min(63, N_NODES - 1 - n0);  // last valid local row
    float bic[4];
#pragma unroll
    for (int cl = 0; cl < 4; ++cl) bic[cl] = bl[w * 64 + cl * 16 + ml];
#pragma unroll
    for (int rt = 0; rt < 4; ++rt) {
      f32x4 acc[4];
#pragma unroll
      for (int cl = 0; cl < 4; ++cl) acc[cl] = (f32x4){0.f, 0.f, 0.f, 0.f};
      const int arow = rt * 16 + ml;
#pragma unroll
      for (int kc = 0; kc < 2; ++kc) {
        short8 a0 = *(const short8*)(&aggT[arow * 18 + kc * 8 + q * 2]);
#pragma unroll
        for (int cl = 0; cl < 4; ++cl) {
          short8 bb = *(const short8*)(Wl_pk + ((size_t)((w * 4 + cl) * 2 + kc) * 64 + lane) * 8);
          acc[cl] = __builtin_amdgcn_mfma_f32_16x16x32_bf16(a0, bb, acc[cl], 0, 0, 0);
        }
        short8 a1 = *(const short8*)((const bf16*)x2 + (size_t)(n0 + arow) * D_IN + kc * 32 + q * 8);
#pragma unroll
        for (int cl = 0; cl < 4; ++cl) {
          short8 bb = *(const short8*)(Wr_pk + ((size_t)((w * 4 + cl) * 2 + kc) * 64 + lane) * 8);
          acc[cl] = __builtin_amdgcn_mfma_f32_16x16x32_bf16(a1, bb, acc[cl], 0, 0, 0);
        }
      }
      // bias + relu, then per-graph masked column sums -> global atomics
      float vv[4][4];
      int bt[4];
#pragma unroll
      for (int i = 0; i < 4; ++i) bt[i] = s_batch[rt * 16 + q * 4 + i];
#pragma unroll
      for (int cl = 0; cl < 4; ++cl)
#pragma unroll
        for (int i = 0; i < 4; ++i)
          vv[cl][i] = fmaxf(acc[cl][i] + bic[cl], 0.f);
      const int glo = s_batch[min(rt * 16, lv)];
      const int ghi = s_batch[min(rt * 16 + 15, lv)];
      for (int g = glo; g <= ghi; ++g) {
#pragma unroll
        for (int cl = 0; cl < 4; ++cl) {
          float s = 0.f;
#pragma unroll
          for (int i = 0; i < 4; ++i) s += (bt[i] == g) ? vv[cl][i] : 0.f;
          s += __shfl_xor(s, 16); s += __shfl_xor(s, 32);
          if (q == 0)
            atomicAdd(&poolsum[(size_t)g * HID + (w * 64 + cl * 16 + ml)], s);
        }
      }
    }
    return;
  }
  // protein GEMM: pe[1024x1280] @ Wp[1280x256], FULL K, 64 blocks x 16 graphs
  const int kb = blockIdx.x - NB;     // 0..63
  const int w = t >> 6, lane = t & 63;
  const int ml = lane & 15, q = lane >> 4;
  const int g0 = kb * 16;
  f32x4 acc[4];
#pragma unroll
  for (int c = 0; c < 4; ++c) acc[c] = (f32x4){0.f, 0.f, 0.f, 0.f};
  for (int kc = 0; kc < 40; ++kc) {
    short8 a = *(const short8*)(pebf + (size_t)(g0 + ml) * D_PROT + kc * 32 + q * 8);
#pragma unroll
    for (int cl = 0; cl < 4; ++cl) {
      short8 bb = *(const short8*)(Wp_pk + ((size_t)((w * 4 + cl) * 40 + kc) * 64 + lane) * 8);
      acc[cl] = __builtin_amdgcn_mfma_f32_16x16x32_bf16(a, bb, acc[cl], 0, 0, 0);
    }
  }
#pragma unroll
  for (int cl = 0; cl < 4; ++cl) {
    const int col = w * 64 + cl * 16 + ml;
    const float bpc = bp[col];
#pragma unroll
    for (int i = 0; i < 4; ++i)
      protC[(size_t)(g0 + q * 4 + i) * HID + col] =
          (unsigned short)bf16rne(acc[cl][i] + bpc);
  }
}

// ---------------------------------------------------------------------------
// k_tail (FUSED finalize): 64 blocks x 16 graphs. Each block builds its own
// 16x512 bf16 A-tile in LDS (pooled mean from poolsum/counts || protC copy),
// then interaction MFMA + bias+relu+(*Wo)+column-reduce head.
// ---------------------------------------------------------------------------
__device__ inline int lb_dev(const int* __restrict__ a, int v) {
  int lo = 0, hi = N_NODES;
  while (lo < hi) { int m = (lo + hi) >> 1; if (a[m] < v) lo = m + 1; else hi = m; }
  return lo;
}

__global__ __launch_bounds__(256) void k_tail(
    const float* __restrict__ poolsum, const int* __restrict__ batch,
    const unsigned short* __restrict__ protC,
    const bf16* __restrict__ Wi_pk, const float* __restrict__ bi,
    const float* __restrict__ Wo, const float* __restrict__ bo,
    float* __restrict__ out) {
  __shared__ bf16 aT[16][520];   // +8 bf16 pad: 2-way (free) bank pattern
  __shared__ float s_inv[16];
  __shared__ float sRed[16 * 4];
  const int t = threadIdx.x, w = t >> 6, lane = t & 63;
  const int ml = lane & 15, q = lane >> 4;
  const int g0 = blockIdx.x * 16;
  if (t < 16) {
    int lo = lb_dev(batch, g0 + t), hi = lb_dev(batch, g0 + t + 1);
    s_inv[t] = 1.0f / (float)max(hi - lo, 1);
  }
  __syncthreads();
  // left half: pooled mean (f32 -> bf16); right half: direct bf16 copy
  for (int idx = t; idx < 16 * 256; idx += 256) {
    const int row = idx >> 8, col = idx & 255;
    float v = poolsum[(size_t)(g0 + row) * HID + col] * s_inv[row];
    ((unsigned short*)&aT[row][0])[col] = (unsigned short)bf16rne(v);
    ((unsigned short*)&aT[row][0])[HID + col] =
        protC[(size_t)(g0 + row) * HID + col];
  }
  __syncthreads();
  f32x4 acc[4];
#pragma unroll
  for (int c = 0; c < 4; ++c) acc[c] = (f32x4){0.f, 0.f, 0.f, 0.f};
  for (int kc = 0; kc < 16; ++kc) {
    short8 a = *(const short8*)(&aT[ml][kc * 32 + q * 8]);
#pragma unroll
    for (int cl = 0; cl < 4; ++cl) {
      short8 bb = *(const short8*)(Wi_pk + ((size_t)((w * 4 + cl) * 16 + kc) * 64 + lane) * 8);
      acc[cl] = __builtin_amdgcn_mfma_f32_16x16x32_bf16(a, bb, acc[cl], 0, 0, 0);
    }
  }
  // epilogue: inter = relu(acc + bi); partial = inter * Wo; reduce over cols
  float bic[4], woc[4];
#pragma unroll
  for (int cl = 0; cl < 4; ++cl) {
    const int col = w * 64 + cl * 16 + ml;
    bic[cl] = bi[col];
    woc[cl] = Wo[col];
  }
#pragma unroll
  for (int i = 0; i < 4; ++i) {
    float s = 0.f;
#pragma unroll
    for (int cl = 0; cl < 4; ++cl)
      s += fmaxf(acc[cl][i] + bic[cl], 0.f) * woc[cl];
    // reduce over the 16 ml lanes (stays within same q group)
    s += __shfl_xor(s, 1); s += __shfl_xor(s, 2);
    s += __shfl_xor(s, 4); s += __shfl_xor(s, 8);
    if (ml == 0) sRed[(q * 4 + i) * 4 + w] = s;
  }
  __syncthreads();
  if (t < 16)
    out[g0 + t] = sRed[t * 4 + 0] + sRed[t * 4 + 1] + sRed[t * 4 + 2]
                + sRed[t * 4 + 3] + bo[0];
}

extern "C" void kernel_launch(void* const* d_in, const int* in_sizes, int n_in,
                              void* d_out, int out_size, void* d_ws, size_t ws_size,
                              hipStream_t stream) {
  const float* x     = (const float*)d_in[0];
  const float* pe    = (const float*)d_in[1];
  const float* Wl    = (const float*)d_in[2];
  const float* bl    = (const float*)d_in[3];
  const float* Wr    = (const float*)d_in[4];
  const float* Wp    = (const float*)d_in[5];
  const float* bp    = (const float*)d_in[6];
  const float* Wi    = (const float*)d_in[7];
  const float* bi    = (const float*)d_in[8];
  const float* Wo    = (const float*)d_in[9];
  const float* bo    = (const float*)d_in[10];
  const int*   ei    = (const int*)d_in[11];
  const int*   batch = (const int*)d_in[12];
  float* out = (float*)d_out;

  char* p = (char*)d_ws;
  auto alloc = [&](size_t bytes) {
    char* r = p;
    p += (bytes + 255) & ~(size_t)255;
    return r;
  };
  int*   bcnt    = (int*)alloc(NB * 4);
  float* poolsum = (float*)alloc((size_t)N_GRAPHS * HID * 4);
  size_t zbytes = (size_t)(p - (char*)d_ws);   // bcnt + poolsum zeroed
  unsigned* bped  = (unsigned*)alloc((size_t)NB * BCAP * 4);
  bf16*  xbf    = (bf16*)alloc((size_t)N_PAD * D_IN * 2);
  bf16*  pebf   = (bf16*)alloc((size_t)N_GRAPHS * D_PROT * 2);
  bf16*  Wl_pk  = (bf16*)alloc((size_t)D_IN * HID * 2);
  bf16*  Wr_pk  = (bf16*)alloc((size_t)D_IN * HID * 2);
  bf16*  Wp_pk  = (bf16*)alloc((size_t)D_PROT * HID * 2);
  bf16*  Wi_pk  = (bf16*)alloc((size_t)2 * HID * HID * 2);
  unsigned short* protC = (unsigned short*)alloc((size_t)N_GRAPHS * HID * 2);

  (void)hipMemsetAsync(d_ws, 0, zbytes, stream);

  k_front<<<BBLK + PREP_WI, 256, 0, stream>>>(
      x, pe, Wl, Wr, Wp, Wi, ei,
      (uint2*)xbf, (uint2*)pebf, Wl_pk, Wr_pk, Wp_pk, Wi_pk, bcnt, bped);
  k_mid<<<NB + 64, 256, 0, stream>>>(
      (const uint2*)xbf, bped, bcnt, batch, Wl_pk, Wr_pk, bl, poolsum,
      pebf, Wp_pk, bp, protC);
  k_tail<<<N_GRAPHS / 16, 256, 0, stream>>>(
      poolsum, batch, protC, Wi_pk, bi, Wo, bo, out);
}